// Round 5
// baseline (340.304 us; speedup 1.0000x reference)
//
#include <hip/hip_runtime.h>
#include <hip/hip_bf16.h>

typedef __attribute__((ext_vector_type(8))) short short8;
typedef __attribute__((ext_vector_type(4))) float f32x4;

#define BB 8
#define NN 32768
#define KK 128
#define DD 64
#define TAU 1.0f
#define ITERS 10
#define EPSV 1e-8f
#define JPARTS 128

// ---- d_out layout (floats) ----
#define G_SZ   ((size_t)BB * NN * KK)
#define PI_OFF (G_SZ)
#define XY_OFF (PI_OFF + (size_t)BB * KK)
#define NF_OUT (XY_OFF + (size_t)BB * KK * 3)

// ---- d_ws layout (floats) ----
#define SLICE_F (BB * KK * 4)                  // 4096
#define SS_OFF  ((ITERS + 1) * SLICE_F)        // 45056
#define HDR_F   (SS_OFF + 16)                  // 45072
#define PART_OFF HDR_F                         // partials: JPARTS*B*K*D floats
#define PART_F  ((size_t)JPARTS * BB * KK * DD)
#define GT_OFF  (PART_OFF + PART_F)            // gammaT bf16: B*K*N ushorts
#define WS_NEED_BYTES  ((PART_OFF + PART_F) * 4)
#define WS_MFMA_BYTES  ((GT_OFF + (size_t)BB * KK * NN / 2) * 4)

__device__ __forceinline__ unsigned pk2(float a, float b) {
    __hip_bfloat162 h = __float22bfloat162_rn(make_float2(a, b));
    unsigned u; __builtin_memcpy(&u, &h, 4); return u;
}

// ================= prep: s_sum + initial centers as acc slice 0 =================
__global__ __launch_bounds__(256) void prep_kernel(const float* __restrict__ xyz,
                                                   const float* __restrict__ sc,
                                                   float* __restrict__ ws) {
    int b = blockIdx.x, tid = threadIdx.x, wave = tid >> 6, lane = tid & 63;
    const float* S = sc + (size_t)b * NN;
    float sum = 0.f;
    for (int i = tid; i < NN; i += 256) sum += S[i];
    #pragma unroll
    for (int m = 1; m <= 32; m <<= 1) sum += __shfl_xor(sum, m, 64);
    __shared__ float red[4];
    if (lane == 0) red[wave] = sum;
    __syncthreads();
    if (tid == 0) ws[SS_OFF + b] = red[0] + red[1] + red[2] + red[3] + EPSV;
    if (tid < KK) {
        const float* X = xyz + (size_t)b * 3 * NN;
        int i0 = tid * (NN / KK);
        ((float4*)ws)[b * KK + tid] =
            make_float4(X[i0], X[NN + i0], X[2 * NN + i0], 1.0f);
    }
}

// ============ assign: 2-pass softmax (pass1 lane-per-point, pass2 k-per-lane) ==
// grid (128, B), block 256; each block owns 256 points.
// LAST additionally emits gamma^T bf16 into gt (if non-null).
template <bool LAST>
__global__ __launch_bounds__(256) void assign_kernel(
    const float* __restrict__ xyz, const float* __restrict__ sc,
    const float4* __restrict__ accIn, float* __restrict__ accOut,
    float* __restrict__ gamma_out, unsigned short* __restrict__ gt)
{
    __shared__ float4 cLds[KK];
    __shared__ float4 wLds[256];
    __shared__ float  accW[4][512];

    const int b = blockIdx.y, blk = blockIdx.x;
    const int tid = threadIdx.x, wave = tid >> 6, lane = tid & 63;

    const float* X = xyz + (size_t)b * 3 * NN;
    const float* S = sc + (size_t)b * NN;

    const int n = blk * 256 + tid;
    const float px = X[n], py = X[NN + n], pz = X[2 * NN + n], ps = S[n];

    if (tid < KK) {
        float4 a = accIn[b * KK + tid];
        float denom = a.w + EPSV;
        float cx = a.x / denom, cy = a.y / denom, cz = a.z / denom;
        cLds[tid] = make_float4(2.f * cx / TAU, 2.f * cy / TAU, 2.f * cz / TAU,
                                -(cx * cx + cy * cy + cz * cz) / TAU);
    }
    __syncthreads();

    // pass 1: own-point softmax denominator via broadcast cLds reads
    float l0 = 0.f, l1 = 0.f;
    #pragma unroll 8
    for (int k = 0; k < KK; k += 2) {
        float4 ca = cLds[k], cb = cLds[k + 1];
        l0 += __expf(fmaf(px, ca.x, fmaf(py, ca.y, fmaf(pz, ca.z, ca.w))));
        l1 += __expf(fmaf(px, cb.x, fmaf(py, cb.y, fmaf(pz, cb.z, cb.w))));
    }
    wLds[tid] = make_float4(px, py, pz, ps / (l0 + l1));
    __syncthreads();

    // pass 2: lane owns clusters lane, lane+64
    const float4 c0 = cLds[lane];
    const float4 c1 = cLds[lane + 64];
    float ax0 = 0, ay0 = 0, az0 = 0, aw0 = 0;
    float ax1 = 0, ay1 = 0, az1 = 0, aw1 = 0;
    float* grow = gamma_out + ((size_t)b * NN + blk * 256 + (wave << 6)) * KK + lane;

    unsigned* r0 = nullptr; unsigned* r1 = nullptr;
    if (LAST) {
        int n0w = blk * 256 + (wave << 6);
        r0 = (unsigned*)gt + ((size_t)b * KK + lane) * (NN / 2) + n0w / 2;
        r1 = r0 + (size_t)64 * (NN / 2);
    }
    unsigned pk0[4], pk1[4];

    #pragma unroll
    for (int jp = 0; jp < 32; ++jp) {
        float4 Pa = wLds[(wave << 6) | (2 * jp)];
        float4 Pb = wLds[(wave << 6) | (2 * jp + 1)];
        float g0a = __expf(fmaf(Pa.x, c0.x, fmaf(Pa.y, c0.y, fmaf(Pa.z, c0.z, c0.w)))) * Pa.w;
        float g1a = __expf(fmaf(Pa.x, c1.x, fmaf(Pa.y, c1.y, fmaf(Pa.z, c1.z, c1.w)))) * Pa.w;
        float g0b = __expf(fmaf(Pb.x, c0.x, fmaf(Pb.y, c0.y, fmaf(Pb.z, c0.z, c0.w)))) * Pb.w;
        float g1b = __expf(fmaf(Pb.x, c1.x, fmaf(Pb.y, c1.y, fmaf(Pb.z, c1.z, c1.w)))) * Pb.w;
        if (LAST) {
            grow[(size_t)(2 * jp) * KK] = g0a;
            grow[(size_t)(2 * jp) * KK + 64] = g1a;
            grow[(size_t)(2 * jp + 1) * KK] = g0b;
            grow[(size_t)(2 * jp + 1) * KK + 64] = g1b;
            pk0[jp & 3] = pk2(g0a, g0b);
            pk1[jp & 3] = pk2(g1a, g1b);
            if ((jp & 3) == 3 && gt) {
                ((uint4*)r0)[jp >> 2] = make_uint4(pk0[0], pk0[1], pk0[2], pk0[3]);
                ((uint4*)r1)[jp >> 2] = make_uint4(pk1[0], pk1[1], pk1[2], pk1[3]);
            }
        }
        ax0 = fmaf(g0a, Pa.x, ax0); ay0 = fmaf(g0a, Pa.y, ay0);
        az0 = fmaf(g0a, Pa.z, az0); aw0 += g0a;
        ax1 = fmaf(g1a, Pa.x, ax1); ay1 = fmaf(g1a, Pa.y, ay1);
        az1 = fmaf(g1a, Pa.z, az1); aw1 += g1a;
        ax0 = fmaf(g0b, Pb.x, ax0); ay0 = fmaf(g0b, Pb.y, ay0);
        az0 = fmaf(g0b, Pb.z, az0); aw0 += g0b;
        ax1 = fmaf(g1b, Pb.x, ax1); ay1 = fmaf(g1b, Pb.y, ay1);
        az1 = fmaf(g1b, Pb.z, az1); aw1 += g1b;
    }

    ((float4*)accW[wave])[lane]      = make_float4(ax0, ay0, az0, aw0);
    ((float4*)accW[wave])[lane + 64] = make_float4(ax1, ay1, az1, aw1);
    __syncthreads();
    float v0 = accW[0][tid]       + accW[1][tid]       + accW[2][tid]       + accW[3][tid];
    float v1 = accW[0][tid + 256] + accW[1][tid + 256] + accW[2][tid + 256] + accW[3][tid + 256];
    float* ag = accOut + b * (KK * 4);
    atomicAdd(ag + tid, v0);
    atomicAdd(ag + tid + 256, v1);
}

// ================= final: node_xyz + pi from slice ITERS =================
__global__ void final_kernel(const float* __restrict__ ws, float* __restrict__ out) {
    int b = blockIdx.x, k = threadIdx.x;
    float4 a = ((const float4*)(ws + ITERS * SLICE_F))[b * KK + k];
    float denom = a.w + EPSV;
    float* oxyz = out + XY_OFF + (size_t)(b * KK + k) * 3;
    oxyz[0] = a.x / denom; oxyz[1] = a.y / denom; oxyz[2] = a.z / denom;
    out[PI_OFF + b * KK + k] = a.w / ws[SS_OFF + b];
}

// ====== nf_mfma: partial nf[k][d] via 16x16x32 bf16 MFMA, no LDS ======
// grid (JPARTS, B), block 256. Wave w: k-rows [32w, 32w+32), all 64 d.
// A = gammaT[k][n] (bf16, direct 16B loads), B = feats[d][n] (f32 -> bf16).
__global__ __launch_bounds__(256) void nf_mfma(const unsigned short* __restrict__ gt,
                                               const float* __restrict__ feats,
                                               float* __restrict__ dst) {
    const int b = blockIdx.y, part = blockIdx.x;
    const int tid = threadIdx.x, wave = tid >> 6, lane = tid & 63;
    const int r = lane & 15, hi = lane >> 4;

    f32x4 acc[2][4];
    #pragma unroll
    for (int kt = 0; kt < 2; kt++)
        #pragma unroll
        for (int dt = 0; dt < 4; dt++) acc[kt][dt] = (f32x4){0.f, 0.f, 0.f, 0.f};

    const unsigned short* gtb = gt + ((size_t)b * KK + wave * 32 + r) * NN;
    const float* fb = feats + (size_t)b * DD * NN;
    const int n0 = part * (NN / JPARTS);

    for (int ch = 0; ch < (NN / JPARTS) / 32; ++ch) {
        const int nn = n0 + ch * 32 + hi * 8;
        short8 a0 = *(const short8*)(gtb + nn);
        short8 a1 = *(const short8*)(gtb + (size_t)16 * NN + nn);
        union { unsigned u[4]; short8 s; } bu[4];
        #pragma unroll
        for (int dt = 0; dt < 4; dt++) {
            const float* fr = fb + (size_t)(dt * 16 + r) * NN + nn;
            float4 x = *(const float4*)fr;
            float4 y = *(const float4*)(fr + 4);
            bu[dt].u[0] = pk2(x.x, x.y); bu[dt].u[1] = pk2(x.z, x.w);
            bu[dt].u[2] = pk2(y.x, y.y); bu[dt].u[3] = pk2(y.z, y.w);
        }
        #pragma unroll
        for (int dt = 0; dt < 4; dt++) {
            acc[0][dt] = __builtin_amdgcn_mfma_f32_16x16x32_bf16(a0, bu[dt].s, acc[0][dt], 0, 0, 0);
            acc[1][dt] = __builtin_amdgcn_mfma_f32_16x16x32_bf16(a1, bu[dt].s, acc[1][dt], 0, 0, 0);
        }
    }

    float* p = dst + ((size_t)(b * JPARTS + part)) * (KK * DD) + (size_t)(wave * 32) * DD;
    #pragma unroll
    for (int kt = 0; kt < 2; kt++)
        #pragma unroll
        for (int dt = 0; dt < 4; dt++)
            #pragma unroll
            for (int rr = 0; rr < 4; rr++)
                p[(kt * 16 + hi * 4 + rr) * DD + dt * 16 + r] = acc[kt][dt][rr];
}

// ====== fallback f32 nf_compute (round-4 proven) ======
template <bool ATOMIC>
__global__ __launch_bounds__(256) void nf_compute(const float* __restrict__ gamma,
                                                  const float* __restrict__ feats,
                                                  float* __restrict__ dst) {
    __shared__ float gLds[32 * 128];
    __shared__ float fLds[64 * 33];
    const int b = blockIdx.y, part = blockIdx.x, tid = threadIdx.x;
    const int kq = (tid & 15) * 8, dg = (tid >> 4) * 4;
    float acc[8][4];
    #pragma unroll
    for (int i = 0; i < 8; i++)
        #pragma unroll
        for (int u = 0; u < 4; u++) acc[i][u] = 0.f;
    const float* gb = gamma + (size_t)b * NN * KK + (size_t)part * (NN / JPARTS) * KK;
    const float* fb = feats + (size_t)b * DD * NN + part * (NN / JPARTS);
    for (int ch = 0; ch < (NN / JPARTS) / 32; ++ch) {
        const float4* gs = (const float4*)(gb + (size_t)ch * 32 * KK);
        #pragma unroll
        for (int i = 0; i < 4; i++) ((float4*)gLds)[tid + i * 256] = gs[tid + i * 256];
        #pragma unroll
        for (int i = 0; i < 2; i++) {
            int idx = tid + i * 256;
            int d = idx >> 3, c4 = (idx & 7) * 4;
            float4 fv = *(const float4*)(fb + (size_t)d * NN + ch * 32 + c4);
            float* fr = &fLds[d * 33 + c4];
            fr[0] = fv.x; fr[1] = fv.y; fr[2] = fv.z; fr[3] = fv.w;
        }
        __syncthreads();
        #pragma unroll 4
        for (int nl = 0; nl < 32; ++nl) {
            float4 g0 = *(const float4*)&gLds[nl * 128 + kq];
            float4 g1 = *(const float4*)&gLds[nl * 128 + kq + 4];
            float fv[4];
            #pragma unroll
            for (int u = 0; u < 4; u++) fv[u] = fLds[(dg + u) * 33 + nl];
            float gk[8] = {g0.x, g0.y, g0.z, g0.w, g1.x, g1.y, g1.z, g1.w};
            #pragma unroll
            for (int i = 0; i < 8; i++)
                #pragma unroll
                for (int u = 0; u < 4; u++)
                    acc[i][u] = fmaf(gk[i], fv[u], acc[i][u]);
        }
        __syncthreads();
    }
    if (ATOMIC) {
        float* nf = dst + (size_t)b * KK * DD;
        #pragma unroll
        for (int i = 0; i < 8; i++)
            #pragma unroll
            for (int u = 0; u < 4; u++)
                atomicAdd(&nf[(kq + i) * DD + dg + u], acc[i][u]);
    } else {
        float* p = dst + ((size_t)(b * JPARTS + part)) * (KK * DD);
        #pragma unroll
        for (int i = 0; i < 8; i++)
            *(float4*)&p[(kq + i) * DD + dg] =
                make_float4(acc[i][0], acc[i][1], acc[i][2], acc[i][3]);
    }
}

// ====== nf_reduce: sum JPARTS partials, divide by denom, write out ======
__global__ __launch_bounds__(256) void nf_reduce(const float* __restrict__ ws,
                                                 float* __restrict__ out) {
    int idx = blockIdx.x * 256 + threadIdx.x;
    int b = idx >> 13, e = idx & 8191;
    const float* p = ws + PART_OFF + (size_t)b * JPARTS * (KK * DD) + e;
    float sum = 0.f;
    #pragma unroll 8
    for (int j = 0; j < JPARTS; ++j) sum += p[(size_t)j * (KK * DD)];
    int k = e >> 6;
    float denom = ws[ITERS * SLICE_F + (b * KK + k) * 4 + 3] + EPSV;
    out[NF_OUT + idx] = sum / denom;
}

__global__ __launch_bounds__(256) void nf_finalize(const float* __restrict__ ws,
                                                   float* __restrict__ out) {
    int idx = blockIdx.x * 256 + threadIdx.x;
    int bk = idx / DD;
    float denom = ws[ITERS * SLICE_F + bk * 4 + 3] + EPSV;
    out[NF_OUT + idx] = out[NF_OUT + idx] / denom;
}

extern "C" void kernel_launch(void* const* d_in, const int* in_sizes, int n_in,
                              void* d_out, int out_size, void* d_ws, size_t ws_size,
                              hipStream_t stream) {
    const float* xyz = (const float*)d_in[0];
    const float* feats = (const float*)d_in[1];
    const float* sc = (const float*)d_in[2];
    float* out = (float*)d_out;
    float* ws = (float*)d_ws;

    const bool mfma_path = ws_size >= WS_MFMA_BYTES;
    unsigned short* gt = mfma_path ? (unsigned short*)(ws + GT_OFF) : nullptr;

    hipMemsetAsync(ws, 0, (size_t)HDR_F * sizeof(float), stream);
    prep_kernel<<<BB, 256, 0, stream>>>(xyz, sc, ws);

    for (int it = 0; it < ITERS - 1; it++) {
        assign_kernel<false><<<dim3(128, BB), 256, 0, stream>>>(
            xyz, sc, (const float4*)(ws + it * SLICE_F),
            ws + (it + 1) * SLICE_F, out, nullptr);
    }
    assign_kernel<true><<<dim3(128, BB), 256, 0, stream>>>(
        xyz, sc, (const float4*)(ws + (ITERS - 1) * SLICE_F),
        ws + ITERS * SLICE_F, out, gt);

    final_kernel<<<BB, KK, 0, stream>>>(ws, out);

    if (mfma_path) {
        nf_mfma<<<dim3(JPARTS, BB), 256, 0, stream>>>(gt, feats, ws + PART_OFF);
        nf_reduce<<<256, 256, 0, stream>>>(ws, out);
    } else if (ws_size >= WS_NEED_BYTES) {
        nf_compute<false><<<dim3(JPARTS, BB), 256, 0, stream>>>(out, feats, ws + PART_OFF);
        nf_reduce<<<256, 256, 0, stream>>>(ws, out);
    } else {
        hipMemsetAsync(out + NF_OUT, 0, (size_t)BB * KK * DD * sizeof(float), stream);
        nf_compute<true><<<dim3(JPARTS, BB), 256, 0, stream>>>(out, feats, out + NF_OUT);
        nf_finalize<<<256, 256, 0, stream>>>(ws, out);
    }
}

// Round 6
// 301.225 us; speedup vs baseline: 1.1297x; 1.1297x over previous
//
#include <hip/hip_runtime.h>
#include <hip/hip_bf16.h>

typedef __attribute__((ext_vector_type(8))) short short8;
typedef __attribute__((ext_vector_type(4))) float f32x4;

#define BB 8
#define NN 32768
#define KK 128
#define DD 64
#define TAU 1.0f
#define ITERS 10
#define EPSV 1e-8f
#define JPARTS 128

// ---- d_out layout (floats) ----
#define G_SZ   ((size_t)BB * NN * KK)
#define PI_OFF (G_SZ)
#define XY_OFF (PI_OFF + (size_t)BB * KK)
#define NF_OUT (XY_OFF + (size_t)BB * KK * 3)

// ---- d_ws layout (floats) ----
#define SLICE_F (BB * KK * 4)                  // 4096
#define SS_OFF  ((ITERS + 1) * SLICE_F)        // 45056
#define HDR_F   (SS_OFF + 16)                  // 45072
#define PART_OFF HDR_F                         // partials: JPARTS*B*K*D floats
#define PART_F  ((size_t)JPARTS * BB * KK * DD)
#define WS_NEED_BYTES  ((PART_OFF + PART_F) * 4)

__device__ __forceinline__ unsigned pk2(float a, float b) {
    __hip_bfloat162 h = __float22bfloat162_rn(make_float2(a, b));
    unsigned u; __builtin_memcpy(&u, &h, 4); return u;
}

// ================= prep: s_sum + initial centers as acc slice 0 =================
__global__ __launch_bounds__(256) void prep_kernel(const float* __restrict__ xyz,
                                                   const float* __restrict__ sc,
                                                   float* __restrict__ ws) {
    int b = blockIdx.x, tid = threadIdx.x, wave = tid >> 6, lane = tid & 63;
    const float* S = sc + (size_t)b * NN;
    float sum = 0.f;
    for (int i = tid; i < NN; i += 256) sum += S[i];
    #pragma unroll
    for (int m = 1; m <= 32; m <<= 1) sum += __shfl_xor(sum, m, 64);
    __shared__ float red[4];
    if (lane == 0) red[wave] = sum;
    __syncthreads();
    if (tid == 0) ws[SS_OFF + b] = red[0] + red[1] + red[2] + red[3] + EPSV;
    if (tid < KK) {
        const float* X = xyz + (size_t)b * 3 * NN;
        int i0 = tid * (NN / KK);
        ((float4*)ws)[b * KK + tid] =
            make_float4(X[i0], X[NN + i0], X[2 * NN + i0], 1.0f);
    }
}

// ============ assign: 2-pass softmax (pass1 lane-per-point, pass2 k-per-lane) ==
// grid (128, B), block 256; each block owns 256 points.  (round-4 proven form)
template <bool LAST>
__global__ __launch_bounds__(256) void assign_kernel(
    const float* __restrict__ xyz, const float* __restrict__ sc,
    const float4* __restrict__ accIn,   // slice it
    float* __restrict__ accOut,         // slice it+1 (pre-zeroed)
    float* __restrict__ gamma_out)
{
    __shared__ float4 cLds[KK];      // {2cx,2cy,2cz,-|c|^2}/tau
    __shared__ float4 wLds[256];     // {x,y,z, s/l}
    __shared__ float  accW[4][512];

    const int b = blockIdx.y, blk = blockIdx.x;
    const int tid = threadIdx.x, wave = tid >> 6, lane = tid & 63;

    const float* X = xyz + (size_t)b * 3 * NN;
    const float* S = sc + (size_t)b * NN;

    const int n = blk * 256 + tid;
    const float px = X[n], py = X[NN + n], pz = X[2 * NN + n], ps = S[n];

    if (tid < KK) {
        float4 a = accIn[b * KK + tid];
        float denom = a.w + EPSV;
        float cx = a.x / denom, cy = a.y / denom, cz = a.z / denom;
        cLds[tid] = make_float4(2.f * cx / TAU, 2.f * cy / TAU, 2.f * cz / TAU,
                                -(cx * cx + cy * cy + cz * cz) / TAU);
    }
    __syncthreads();

    // pass 1: own-point softmax denominator via broadcast cLds reads
    float l0 = 0.f, l1 = 0.f;
    #pragma unroll 8
    for (int k = 0; k < KK; k += 2) {
        float4 ca = cLds[k], cb = cLds[k + 1];
        l0 += __expf(fmaf(px, ca.x, fmaf(py, ca.y, fmaf(pz, ca.z, ca.w))));
        l1 += __expf(fmaf(px, cb.x, fmaf(py, cb.y, fmaf(pz, cb.z, cb.w))));
    }
    wLds[tid] = make_float4(px, py, pz, ps / (l0 + l1));
    __syncthreads();

    // pass 2: lane owns clusters lane, lane+64
    const float4 c0 = cLds[lane];
    const float4 c1 = cLds[lane + 64];
    float ax0 = 0, ay0 = 0, az0 = 0, aw0 = 0;
    float ax1 = 0, ay1 = 0, az1 = 0, aw1 = 0;
    float* grow = gamma_out + ((size_t)b * NN + blk * 256 + (wave << 6)) * KK + lane;

    #pragma unroll 4
    for (int j = 0; j < 64; ++j) {
        float4 P = wLds[(wave << 6) | j];   // wave-uniform broadcast
        float g0 = __expf(fmaf(P.x, c0.x, fmaf(P.y, c0.y, fmaf(P.z, c0.z, c0.w)))) * P.w;
        float g1 = __expf(fmaf(P.x, c1.x, fmaf(P.y, c1.y, fmaf(P.z, c1.z, c1.w)))) * P.w;
        if (LAST) {
            grow[(size_t)j * KK] = g0;
            grow[(size_t)j * KK + 64] = g1;
        }
        ax0 = fmaf(g0, P.x, ax0); ay0 = fmaf(g0, P.y, ay0);
        az0 = fmaf(g0, P.z, az0); aw0 += g0;
        ax1 = fmaf(g1, P.x, ax1); ay1 = fmaf(g1, P.y, ay1);
        az1 = fmaf(g1, P.z, az1); aw1 += g1;
    }

    ((float4*)accW[wave])[lane]      = make_float4(ax0, ay0, az0, aw0);
    ((float4*)accW[wave])[lane + 64] = make_float4(ax1, ay1, az1, aw1);
    __syncthreads();
    float v0 = accW[0][tid]       + accW[1][tid]       + accW[2][tid]       + accW[3][tid];
    float v1 = accW[0][tid + 256] + accW[1][tid + 256] + accW[2][tid + 256] + accW[3][tid + 256];
    float* ag = accOut + b * (KK * 4);
    atomicAdd(ag + tid, v0);
    atomicAdd(ag + tid + 256, v1);
}

// ================= final: node_xyz + pi from slice ITERS =================
__global__ void final_kernel(const float* __restrict__ ws, float* __restrict__ out) {
    int b = blockIdx.x, k = threadIdx.x;
    float4 a = ((const float4*)(ws + ITERS * SLICE_F))[b * KK + k];
    float denom = a.w + EPSV;
    float* oxyz = out + XY_OFF + (size_t)(b * KK + k) * 3;
    oxyz[0] = a.x / denom; oxyz[1] = a.y / denom; oxyz[2] = a.z / denom;
    out[PI_OFF + b * KK + k] = a.w / ws[SS_OFF + b];
}

// ====== nf_mfma2: partial nf[k][d] via 16x16x32 bf16 MFMA ======
// grid (JPARTS, B), block 256 (4 waves). Reads gamma f32 [n][k] from d_out,
// stages transposed bf16 gT[k][n] in LDS (pitch 20 dw = 80 B -> 2-way banks).
// Wave w owns k-tiles 2w, 2w+1 (rows 32w..32w+31), all 64 d.
__global__ __launch_bounds__(256) void nf_mfma2(const float* __restrict__ gamma,
                                                const float* __restrict__ feats,
                                                float* __restrict__ dst) {
    __shared__ unsigned short gT[KK * 40];   // [k][pitch 40 bf16], 10240 B
    const int b = blockIdx.y, part = blockIdx.x;
    const int tid = threadIdx.x, wave = tid >> 6, lane = tid & 63;
    const int r = lane & 15, hi = lane >> 4;
    const int p = tid & 15, q0 = tid >> 4;

    f32x4 acc[2][4];
    #pragma unroll
    for (int kt = 0; kt < 2; kt++)
        #pragma unroll
        for (int dt = 0; dt < 4; dt++) acc[kt][dt] = (f32x4){0.f, 0.f, 0.f, 0.f};

    const float* gb = gamma + (size_t)b * NN * KK + (size_t)part * 256 * KK;
    const float* fb = feats + (size_t)b * DD * NN;
    const int n0 = part * 256;

    for (int ch = 0; ch < 8; ++ch) {
        // ---- stage 32 n x 128 k, transposed, f32 -> bf16 ----
        const float* gr0 = gb + (size_t)(ch * 32 + 2 * p) * KK;
        const float* gr1 = gr0 + KK;
        unsigned* rowd = (unsigned*)gT;      // dword view, 20 dw per k-row
        #pragma unroll
        for (int s = 0; s < 2; ++s) {
            int q = q0 + 16 * s;             // k-quad: k = 4q..4q+3
            float4 x = *(const float4*)(gr0 + 4 * q);
            float4 y = *(const float4*)(gr1 + 4 * q);
            rowd[(4 * q + 0) * 20 + p] = pk2(x.x, y.x);
            rowd[(4 * q + 1) * 20 + p] = pk2(x.y, y.y);
            rowd[(4 * q + 2) * 20 + p] = pk2(x.z, y.z);
            rowd[(4 * q + 3) * 20 + p] = pk2(x.w, y.w);
        }
        __syncthreads();

        // ---- frags + MFMA ----
        const unsigned short* a0p = gT + (wave * 32 + r) * 40 + hi * 8;
        short8 a0 = *(const short8*)a0p;
        short8 a1 = *(const short8*)(a0p + 16 * 40);
        const int nn = n0 + ch * 32 + hi * 8;
        #pragma unroll
        for (int dt = 0; dt < 4; ++dt) {
            const float* fr = fb + (size_t)(dt * 16 + r) * NN + nn;
            float4 x = *(const float4*)fr;
            float4 y = *(const float4*)(fr + 4);
            union { unsigned u[4]; short8 s; } bu;
            bu.u[0] = pk2(x.x, x.y); bu.u[1] = pk2(x.z, x.w);
            bu.u[2] = pk2(y.x, y.y); bu.u[3] = pk2(y.z, y.w);
            acc[0][dt] = __builtin_amdgcn_mfma_f32_16x16x32_bf16(a0, bu.s, acc[0][dt], 0, 0, 0);
            acc[1][dt] = __builtin_amdgcn_mfma_f32_16x16x32_bf16(a1, bu.s, acc[1][dt], 0, 0, 0);
        }
        __syncthreads();
    }

    float* pdst = dst + ((size_t)(b * JPARTS + part)) * (KK * DD) + (size_t)(wave * 32) * DD;
    #pragma unroll
    for (int kt = 0; kt < 2; kt++)
        #pragma unroll
        for (int dt = 0; dt < 4; dt++)
            #pragma unroll
            for (int rr = 0; rr < 4; rr++)
                pdst[(kt * 16 + hi * 4 + rr) * DD + dt * 16 + r] = acc[kt][dt][rr];
}

// ====== fallback f32 nf_compute (round-4 proven), atomic variant ======
__global__ __launch_bounds__(256) void nf_compute_atomic(const float* __restrict__ gamma,
                                                         const float* __restrict__ feats,
                                                         float* __restrict__ dst) {
    __shared__ float gLds[32 * 128];
    __shared__ float fLds[64 * 33];
    const int b = blockIdx.y, part = blockIdx.x, tid = threadIdx.x;
    const int kq = (tid & 15) * 8, dg = (tid >> 4) * 4;
    float acc[8][4];
    #pragma unroll
    for (int i = 0; i < 8; i++)
        #pragma unroll
        for (int u = 0; u < 4; u++) acc[i][u] = 0.f;
    const float* gb = gamma + (size_t)b * NN * KK + (size_t)part * (NN / JPARTS) * KK;
    const float* fb = feats + (size_t)b * DD * NN + part * (NN / JPARTS);
    for (int ch = 0; ch < (NN / JPARTS) / 32; ++ch) {
        const float4* gs = (const float4*)(gb + (size_t)ch * 32 * KK);
        #pragma unroll
        for (int i = 0; i < 4; i++) ((float4*)gLds)[tid + i * 256] = gs[tid + i * 256];
        #pragma unroll
        for (int i = 0; i < 2; i++) {
            int idx = tid + i * 256;
            int d = idx >> 3, c4 = (idx & 7) * 4;
            float4 fv = *(const float4*)(fb + (size_t)d * NN + ch * 32 + c4);
            float* fr = &fLds[d * 33 + c4];
            fr[0] = fv.x; fr[1] = fv.y; fr[2] = fv.z; fr[3] = fv.w;
        }
        __syncthreads();
        #pragma unroll 4
        for (int nl = 0; nl < 32; ++nl) {
            float4 g0 = *(const float4*)&gLds[nl * 128 + kq];
            float4 g1 = *(const float4*)&gLds[nl * 128 + kq + 4];
            float fv[4];
            #pragma unroll
            for (int u = 0; u < 4; u++) fv[u] = fLds[(dg + u) * 33 + nl];
            float gk[8] = {g0.x, g0.y, g0.z, g0.w, g1.x, g1.y, g1.z, g1.w};
            #pragma unroll
            for (int i = 0; i < 8; i++)
                #pragma unroll
                for (int u = 0; u < 4; u++)
                    acc[i][u] = fmaf(gk[i], fv[u], acc[i][u]);
        }
        __syncthreads();
    }
    float* nf = dst + (size_t)b * KK * DD;
    #pragma unroll
    for (int i = 0; i < 8; i++)
        #pragma unroll
        for (int u = 0; u < 4; u++)
            atomicAdd(&nf[(kq + i) * DD + dg + u], acc[i][u]);
}

// ====== nf_reduce: sum JPARTS partials, divide by denom, write out ======
__global__ __launch_bounds__(256) void nf_reduce(const float* __restrict__ ws,
                                                 float* __restrict__ out) {
    int idx = blockIdx.x * 256 + threadIdx.x;
    int b = idx >> 13, e = idx & 8191;
    const float* p = ws + PART_OFF + (size_t)b * JPARTS * (KK * DD) + e;
    float sum = 0.f;
    #pragma unroll 8
    for (int j = 0; j < JPARTS; ++j) sum += p[(size_t)j * (KK * DD)];
    int k = e >> 6;
    float denom = ws[ITERS * SLICE_F + (b * KK + k) * 4 + 3] + EPSV;
    out[NF_OUT + idx] = sum / denom;
}

__global__ __launch_bounds__(256) void nf_finalize(const float* __restrict__ ws,
                                                   float* __restrict__ out) {
    int idx = blockIdx.x * 256 + threadIdx.x;
    int bk = idx / DD;
    float denom = ws[ITERS * SLICE_F + bk * 4 + 3] + EPSV;
    out[NF_OUT + idx] = out[NF_OUT + idx] / denom;
}

extern "C" void kernel_launch(void* const* d_in, const int* in_sizes, int n_in,
                              void* d_out, int out_size, void* d_ws, size_t ws_size,
                              hipStream_t stream) {
    const float* xyz = (const float*)d_in[0];
    const float* feats = (const float*)d_in[1];
    const float* sc = (const float*)d_in[2];
    float* out = (float*)d_out;
    float* ws = (float*)d_ws;

    hipMemsetAsync(ws, 0, (size_t)HDR_F * sizeof(float), stream);
    prep_kernel<<<BB, 256, 0, stream>>>(xyz, sc, ws);

    for (int it = 0; it < ITERS - 1; it++) {
        assign_kernel<false><<<dim3(128, BB), 256, 0, stream>>>(
            xyz, sc, (const float4*)(ws + it * SLICE_F),
            ws + (it + 1) * SLICE_F, out);
    }
    assign_kernel<true><<<dim3(128, BB), 256, 0, stream>>>(
        xyz, sc, (const float4*)(ws + (ITERS - 1) * SLICE_F),
        ws + ITERS * SLICE_F, out);

    final_kernel<<<BB, KK, 0, stream>>>(ws, out);

    if (ws_size >= WS_NEED_BYTES) {
        nf_mfma2<<<dim3(JPARTS, BB), 256, 0, stream>>>(out, feats, ws + PART_OFF);
        nf_reduce<<<256, 256, 0, stream>>>(ws, out);
    } else {
        hipMemsetAsync(out + NF_OUT, 0, (size_t)BB * KK * DD * sizeof(float), stream);
        nf_compute_atomic<<<dim3(JPARTS, BB), 256, 0, stream>>>(out, feats, out + NF_OUT);
        nf_finalize<<<256, 256, 0, stream>>>(ws, out);
    }
}

// Round 7
// 294.898 us; speedup vs baseline: 1.1540x; 1.0215x over previous
//
#include <hip/hip_runtime.h>
#include <hip/hip_bf16.h>

typedef __attribute__((ext_vector_type(8))) short short8;
typedef __attribute__((ext_vector_type(4))) float f32x4;

#define BB 8
#define NN 32768
#define KK 128
#define DD 64
#define TAU 1.0f
#define ITERS 10
#define EPSV 1e-8f
#define JPARTS 128

// ---- d_out layout (floats) ----
#define G_SZ   ((size_t)BB * NN * KK)
#define PI_OFF (G_SZ)
#define XY_OFF (PI_OFF + (size_t)BB * KK)
#define NF_OUT (XY_OFF + (size_t)BB * KK * 3)

// ---- d_ws layout (floats) ----
#define SLICE_F (BB * KK * 4)                  // 4096
#define SS_OFF  ((ITERS + 1) * SLICE_F)        // 45056
#define HDR_F   (SS_OFF + 16)                  // 45072
#define PART_OFF HDR_F                         // partials: JPARTS*B*K*D floats
#define PART_F  ((size_t)JPARTS * BB * KK * DD)
#define WS_NEED_BYTES  ((PART_OFF + PART_F) * 4)

__device__ __forceinline__ unsigned pk2(float a, float b) {
    __hip_bfloat162 h = __float22bfloat162_rn(make_float2(a, b));
    unsigned u; __builtin_memcpy(&u, &h, 4); return u;
}

// ================= prep: s_sum + initial centers as acc slice 0 =================
__global__ __launch_bounds__(256) void prep_kernel(const float* __restrict__ xyz,
                                                   const float* __restrict__ sc,
                                                   float* __restrict__ ws) {
    int b = blockIdx.x, tid = threadIdx.x, wave = tid >> 6, lane = tid & 63;
    const float* S = sc + (size_t)b * NN;
    float sum = 0.f;
    for (int i = tid; i < NN; i += 256) sum += S[i];
    #pragma unroll
    for (int m = 1; m <= 32; m <<= 1) sum += __shfl_xor(sum, m, 64);
    __shared__ float red[4];
    if (lane == 0) red[wave] = sum;
    __syncthreads();
    if (tid == 0) ws[SS_OFF + b] = red[0] + red[1] + red[2] + red[3] + EPSV;
    if (tid < KK) {
        const float* X = xyz + (size_t)b * 3 * NN;
        int i0 = tid * (NN / KK);
        ((float4*)ws)[b * KK + tid] =
            make_float4(X[i0], X[NN + i0], X[2 * NN + i0], 1.0f);
    }
}

// ============ assign: 512 points/block, 2-pass softmax ==========================
// grid (64, B), block 256. pass1: 2 points/thread per cLds read (amortized).
// pass2: wave w owns points [w*128, w*128+128), lane owns clusters lane, lane+64.
template <bool LAST>
__global__ __launch_bounds__(256) void assign_kernel(
    const float* __restrict__ xyz, const float* __restrict__ sc,
    const float4* __restrict__ accIn,   // slice it
    float* __restrict__ accOut,         // slice it+1 (pre-zeroed)
    float* __restrict__ gamma_out)
{
    __shared__ float4 cLds[KK];      // {2cx,2cy,2cz,-|c|^2}/tau
    __shared__ float4 wLds[512];     // {x,y,z, s/l}
    __shared__ float  accW[4][512];

    const int b = blockIdx.y, blk = blockIdx.x;
    const int tid = threadIdx.x, wave = tid >> 6, lane = tid & 63;

    const float* X = xyz + (size_t)b * 3 * NN;
    const float* S = sc + (size_t)b * NN;

    const int n = blk * 512 + tid;
    const float px0 = X[n],       py0 = X[NN + n],       pz0 = X[2 * NN + n],       ps0 = S[n];
    const float px1 = X[n + 256], py1 = X[NN + n + 256], pz1 = X[2 * NN + n + 256], ps1 = S[n + 256];

    if (tid < KK) {
        float4 a = accIn[b * KK + tid];
        float denom = a.w + EPSV;
        float cx = a.x / denom, cy = a.y / denom, cz = a.z / denom;
        cLds[tid] = make_float4(2.f * cx / TAU, 2.f * cy / TAU, 2.f * cz / TAU,
                                -(cx * cx + cy * cy + cz * cz) / TAU);
    }
    __syncthreads();

    // pass 1: softmax denominators for 2 points per thread (one cLds read pair
    // serves both points -> LDS traffic per point halved; 4 indep exp chains).
    float l0a = 0.f, l0b = 0.f, l1a = 0.f, l1b = 0.f;
    #pragma unroll 8
    for (int k = 0; k < KK; k += 2) {
        float4 ca = cLds[k], cb = cLds[k + 1];
        l0a += __expf(fmaf(px0, ca.x, fmaf(py0, ca.y, fmaf(pz0, ca.z, ca.w))));
        l1a += __expf(fmaf(px1, ca.x, fmaf(py1, ca.y, fmaf(pz1, ca.z, ca.w))));
        l0b += __expf(fmaf(px0, cb.x, fmaf(py0, cb.y, fmaf(pz0, cb.z, cb.w))));
        l1b += __expf(fmaf(px1, cb.x, fmaf(py1, cb.y, fmaf(pz1, cb.z, cb.w))));
    }
    wLds[tid]       = make_float4(px0, py0, pz0, ps0 / (l0a + l0b));
    wLds[tid + 256] = make_float4(px1, py1, pz1, ps1 / (l1a + l1b));
    __syncthreads();

    // pass 2: lane owns clusters lane, lane+64; wave sweeps its 128 points.
    const float4 c0 = cLds[lane];
    const float4 c1 = cLds[lane + 64];
    float ax0 = 0, ay0 = 0, az0 = 0, aw0 = 0;
    float ax1 = 0, ay1 = 0, az1 = 0, aw1 = 0;
    float* grow = gamma_out + ((size_t)b * NN + blk * 512 + (wave << 7)) * KK + lane;

    #pragma unroll 4
    for (int j = 0; j < 128; ++j) {
        float4 P = wLds[(wave << 7) | j];   // wave-uniform broadcast
        float g0 = __expf(fmaf(P.x, c0.x, fmaf(P.y, c0.y, fmaf(P.z, c0.z, c0.w)))) * P.w;
        float g1 = __expf(fmaf(P.x, c1.x, fmaf(P.y, c1.y, fmaf(P.z, c1.z, c1.w)))) * P.w;
        if (LAST) {
            grow[(size_t)j * KK] = g0;
            grow[(size_t)j * KK + 64] = g1;
        }
        ax0 = fmaf(g0, P.x, ax0); ay0 = fmaf(g0, P.y, ay0);
        az0 = fmaf(g0, P.z, az0); aw0 += g0;
        ax1 = fmaf(g1, P.x, ax1); ay1 = fmaf(g1, P.y, ay1);
        az1 = fmaf(g1, P.z, az1); aw1 += g1;
    }

    ((float4*)accW[wave])[lane]      = make_float4(ax0, ay0, az0, aw0);
    ((float4*)accW[wave])[lane + 64] = make_float4(ax1, ay1, az1, aw1);
    __syncthreads();
    float v0 = accW[0][tid]       + accW[1][tid]       + accW[2][tid]       + accW[3][tid];
    float v1 = accW[0][tid + 256] + accW[1][tid + 256] + accW[2][tid + 256] + accW[3][tid + 256];
    float* ag = accOut + b * (KK * 4);
    atomicAdd(ag + tid, v0);
    atomicAdd(ag + tid + 256, v1);
}

// ================= final: node_xyz + pi from slice ITERS =================
__global__ void final_kernel(const float* __restrict__ ws, float* __restrict__ out) {
    int b = blockIdx.x, k = threadIdx.x;
    float4 a = ((const float4*)(ws + ITERS * SLICE_F))[b * KK + k];
    float denom = a.w + EPSV;
    float* oxyz = out + XY_OFF + (size_t)(b * KK + k) * 3;
    oxyz[0] = a.x / denom; oxyz[1] = a.y / denom; oxyz[2] = a.z / denom;
    out[PI_OFF + b * KK + k] = a.w / ws[SS_OFF + b];
}

// ====== nf_mfma2: partial nf[k][d] via 16x16x32 bf16 MFMA (round-6 proven) =====
__global__ __launch_bounds__(256) void nf_mfma2(const float* __restrict__ gamma,
                                                const float* __restrict__ feats,
                                                float* __restrict__ dst) {
    __shared__ unsigned short gT[KK * 40];   // [k][pitch 40 bf16], 10240 B
    const int b = blockIdx.y, part = blockIdx.x;
    const int tid = threadIdx.x, wave = tid >> 6, lane = tid & 63;
    const int r = lane & 15, hi = lane >> 4;
    const int p = tid & 15, q0 = tid >> 4;

    f32x4 acc[2][4];
    #pragma unroll
    for (int kt = 0; kt < 2; kt++)
        #pragma unroll
        for (int dt = 0; dt < 4; dt++) acc[kt][dt] = (f32x4){0.f, 0.f, 0.f, 0.f};

    const float* gb = gamma + (size_t)b * NN * KK + (size_t)part * 256 * KK;
    const float* fb = feats + (size_t)b * DD * NN;
    const int n0 = part * 256;

    for (int ch = 0; ch < 8; ++ch) {
        const float* gr0 = gb + (size_t)(ch * 32 + 2 * p) * KK;
        const float* gr1 = gr0 + KK;
        unsigned* rowd = (unsigned*)gT;
        #pragma unroll
        for (int s = 0; s < 2; ++s) {
            int q = q0 + 16 * s;
            float4 x = *(const float4*)(gr0 + 4 * q);
            float4 y = *(const float4*)(gr1 + 4 * q);
            rowd[(4 * q + 0) * 20 + p] = pk2(x.x, y.x);
            rowd[(4 * q + 1) * 20 + p] = pk2(x.y, y.y);
            rowd[(4 * q + 2) * 20 + p] = pk2(x.z, y.z);
            rowd[(4 * q + 3) * 20 + p] = pk2(x.w, y.w);
        }
        __syncthreads();

        const unsigned short* a0p = gT + (wave * 32 + r) * 40 + hi * 8;
        short8 a0 = *(const short8*)a0p;
        short8 a1 = *(const short8*)(a0p + 16 * 40);
        const int nn = n0 + ch * 32 + hi * 8;
        #pragma unroll
        for (int dt = 0; dt < 4; ++dt) {
            const float* fr = fb + (size_t)(dt * 16 + r) * NN + nn;
            float4 x = *(const float4*)fr;
            float4 y = *(const float4*)(fr + 4);
            union { unsigned u[4]; short8 s; } bu;
            bu.u[0] = pk2(x.x, x.y); bu.u[1] = pk2(x.z, x.w);
            bu.u[2] = pk2(y.x, y.y); bu.u[3] = pk2(y.z, y.w);
            acc[0][dt] = __builtin_amdgcn_mfma_f32_16x16x32_bf16(a0, bu.s, acc[0][dt], 0, 0, 0);
            acc[1][dt] = __builtin_amdgcn_mfma_f32_16x16x32_bf16(a1, bu.s, acc[1][dt], 0, 0, 0);
        }
        __syncthreads();
    }

    float* pdst = dst + ((size_t)(b * JPARTS + part)) * (KK * DD) + (size_t)(wave * 32) * DD;
    #pragma unroll
    for (int kt = 0; kt < 2; kt++)
        #pragma unroll
        for (int dt = 0; dt < 4; dt++)
            #pragma unroll
            for (int rr = 0; rr < 4; rr++)
                pdst[(kt * 16 + hi * 4 + rr) * DD + dt * 16 + r] = acc[kt][dt][rr];
}

// ====== fallback f32 nf_compute (round-4 proven), atomic variant ======
__global__ __launch_bounds__(256) void nf_compute_atomic(const float* __restrict__ gamma,
                                                         const float* __restrict__ feats,
                                                         float* __restrict__ dst) {
    __shared__ float gLds[32 * 128];
    __shared__ float fLds[64 * 33];
    const int b = blockIdx.y, part = blockIdx.x, tid = threadIdx.x;
    const int kq = (tid & 15) * 8, dg = (tid >> 4) * 4;
    float acc[8][4];
    #pragma unroll
    for (int i = 0; i < 8; i++)
        #pragma unroll
        for (int u = 0; u < 4; u++) acc[i][u] = 0.f;
    const float* gb = gamma + (size_t)b * NN * KK + (size_t)part * (NN / JPARTS) * KK;
    const float* fb = feats + (size_t)b * DD * NN + part * (NN / JPARTS);
    for (int ch = 0; ch < (NN / JPARTS) / 32; ++ch) {
        const float4* gs = (const float4*)(gb + (size_t)ch * 32 * KK);
        #pragma unroll
        for (int i = 0; i < 4; i++) ((float4*)gLds)[tid + i * 256] = gs[tid + i * 256];
        #pragma unroll
        for (int i = 0; i < 2; i++) {
            int idx = tid + i * 256;
            int d = idx >> 3, c4 = (idx & 7) * 4;
            float4 fv = *(const float4*)(fb + (size_t)d * NN + ch * 32 + c4);
            float* fr = &fLds[d * 33 + c4];
            fr[0] = fv.x; fr[1] = fv.y; fr[2] = fv.z; fr[3] = fv.w;
        }
        __syncthreads();
        #pragma unroll 4
        for (int nl = 0; nl < 32; ++nl) {
            float4 g0 = *(const float4*)&gLds[nl * 128 + kq];
            float4 g1 = *(const float4*)&gLds[nl * 128 + kq + 4];
            float fv[4];
            #pragma unroll
            for (int u = 0; u < 4; u++) fv[u] = fLds[(dg + u) * 33 + nl];
            float gk[8] = {g0.x, g0.y, g0.z, g0.w, g1.x, g1.y, g1.z, g1.w};
            #pragma unroll
            for (int i = 0; i < 8; i++)
                #pragma unroll
                for (int u = 0; u < 4; u++)
                    acc[i][u] = fmaf(gk[i], fv[u], acc[i][u]);
        }
        __syncthreads();
    }
    float* nf = dst + (size_t)b * KK * DD;
    #pragma unroll
    for (int i = 0; i < 8; i++)
        #pragma unroll
        for (int u = 0; u < 4; u++)
            atomicAdd(&nf[(kq + i) * DD + dg + u], acc[i][u]);
}

// ====== nf_reduce: sum JPARTS partials, divide by denom, write out ======
__global__ __launch_bounds__(256) void nf_reduce(const float* __restrict__ ws,
                                                 float* __restrict__ out) {
    int idx = blockIdx.x * 256 + threadIdx.x;
    int b = idx >> 13, e = idx & 8191;
    const float* p = ws + PART_OFF + (size_t)b * JPARTS * (KK * DD) + e;
    float sum = 0.f;
    #pragma unroll 8
    for (int j = 0; j < JPARTS; ++j) sum += p[(size_t)j * (KK * DD)];
    int k = e >> 6;
    float denom = ws[ITERS * SLICE_F + (b * KK + k) * 4 + 3] + EPSV;
    out[NF_OUT + idx] = sum / denom;
}

__global__ __launch_bounds__(256) void nf_finalize(const float* __restrict__ ws,
                                                   float* __restrict__ out) {
    int idx = blockIdx.x * 256 + threadIdx.x;
    int bk = idx / DD;
    float denom = ws[ITERS * SLICE_F + bk * 4 + 3] + EPSV;
    out[NF_OUT + idx] = out[NF_OUT + idx] / denom;
}

extern "C" void kernel_launch(void* const* d_in, const int* in_sizes, int n_in,
                              void* d_out, int out_size, void* d_ws, size_t ws_size,
                              hipStream_t stream) {
    const float* xyz = (const float*)d_in[0];
    const float* feats = (const float*)d_in[1];
    const float* sc = (const float*)d_in[2];
    float* out = (float*)d_out;
    float* ws = (float*)d_ws;

    hipMemsetAsync(ws, 0, (size_t)HDR_F * sizeof(float), stream);
    prep_kernel<<<BB, 256, 0, stream>>>(xyz, sc, ws);

    for (int it = 0; it < ITERS - 1; it++) {
        assign_kernel<false><<<dim3(64, BB), 256, 0, stream>>>(
            xyz, sc, (const float4*)(ws + it * SLICE_F),
            ws + (it + 1) * SLICE_F, out);
    }
    assign_kernel<true><<<dim3(64, BB), 256, 0, stream>>>(
        xyz, sc, (const float4*)(ws + (ITERS - 1) * SLICE_F),
        ws + ITERS * SLICE_F, out);

    final_kernel<<<BB, KK, 0, stream>>>(ws, out);

    if (ws_size >= WS_NEED_BYTES) {
        nf_mfma2<<<dim3(JPARTS, BB), 256, 0, stream>>>(out, feats, ws + PART_OFF);
        nf_reduce<<<256, 256, 0, stream>>>(ws, out);
    } else {
        hipMemsetAsync(out + NF_OUT, 0, (size_t)BB * KK * DD * sizeof(float), stream);
        nf_compute_atomic<<<dim3(JPARTS, BB), 256, 0, stream>>>(out, feats, out + NF_OUT);
        nf_finalize<<<256, 256, 0, stream>>>(ws, out);
    }
}